// Round 12
// baseline (396.070 us; speedup 1.0000x reference)
//
#include <hip/hip_runtime.h>
#include <cstdint>
#include <cstddef>

#define N_NODES 8192
#define N_EDGES 131072
#define F_IN    512
#define H1C     32
#define H2C     16

// ---------------- helpers ----------------

__device__ __forceinline__ float block_reduce_sum(float v, int nthreads) {
    #pragma unroll
    for (int off = 32; off; off >>= 1) v += __shfl_down(v, off, 64);
    __shared__ float sred[16];
    int lane = threadIdx.x & 63, wid = threadIdx.x >> 6;
    if (lane == 0) sred[wid] = v;
    __syncthreads();
    float s = 0.0f;
    if (threadIdx.x == 0) {
        int nw = nthreads >> 6;
        for (int i = 0; i < nw; ++i) s += sred[i];
    }
    return s;
}

// POS_WEIGHT=10: y=1 -> 10*softplus(-l); y=0 -> softplus(l).
// Branch-free: sp(l) = lse + relu(l);  val = sp(l)*(1+9y) - 10*y*l
__device__ __forceinline__ float bce_elem(float l, int y) {
    float lse = __logf(1.0f + __expf(-fabsf(l)));
    float sp  = lse + fmaxf(l, 0.0f);
    float w   = (float)y;
    return fmaf(sp, fmaf(9.0f, w, 1.0f), -10.0f * w * l);
}

// force a wave-uniform float into an SGPR
__device__ __forceinline__ float rfl(float x) {
    return __int_as_float(__builtin_amdgcn_readfirstlane(__float_as_int(x)));
}

// ---------------- kernels ----------------

// zero deg + cursor (contiguous 64 KB = 4096 float4)
__global__ void k_init(float4* __restrict__ p) {
    int gid = blockIdx.x * 256 + threadIdx.x;
    float4 zz = {0.0f, 0.0f, 0.0f, 0.0f};
    p[gid] = zz;
}

__global__ void k_deg(const int* __restrict__ dst, int* __restrict__ deg) {
    int e = blockIdx.x * 256 + threadIdx.x;
    if (e < N_EDGES) atomicAdd(&deg[dst[e]], 1);
}

// exclusive scan of deg[8192] -> rowptr[8193]; single block of 256 threads
__global__ void k_scan(const int* __restrict__ deg, int* __restrict__ rowptr) {
    __shared__ int part[256];
    __shared__ int pref[257];
    int t = threadIdx.x;
    int base = t * 32;
    int vals[32];
    int s = 0;
    #pragma unroll
    for (int j = 0; j < 32; ++j) { vals[j] = deg[base + j]; s += vals[j]; }
    part[t] = s;
    __syncthreads();
    if (t == 0) {
        int run = 0;
        for (int i = 0; i < 256; ++i) { pref[i] = run; run += part[i]; }
        pref[256] = run;
    }
    __syncthreads();
    int run = pref[t];
    #pragma unroll
    for (int j = 0; j < 32; ++j) { rowptr[base + j] = run; run += vals[j]; }
    if (t == 255) rowptr[8192] = pref[256];
}

// bucket edges by dst: csr_src[slot] = src[e]  (131K int atomics on cursor)
__global__ void k_fill(const int* __restrict__ src, const int* __restrict__ dst,
                       const int* __restrict__ rowptr, int* __restrict__ cursor,
                       int* __restrict__ csr_src) {
    int e = blockIdx.x * 256 + threadIdx.x;
    int d = dst[e];
    int slot = rowptr[d] + atomicAdd(&cursor[d], 1);
    csr_src[slot] = src[e];
}

// PROBE: pure linear stream of adj (fill-kernel access shape, read direction).
// 2048 blocks x 256 threads x 32 int4 = 16M int4 = 268 MB.
__global__ void k_stream(const int4* __restrict__ a, int* __restrict__ sink) {
    size_t i = (size_t)blockIdx.x * 256 + threadIdx.x;
    int sx = 0, sy = 0, sz = 0, sw = 0;
    #pragma unroll 4
    for (int it = 0; it < 32; ++it) {
        int4 v = a[i + (size_t)it * 524288];
        sx += v.x; sy += v.y; sz += v.z; sw += v.w;
    }
    sink[i] = sx + sy + sz + sw;
}

// h = x @ W1 : [8192,512] x [512,32], 32-row tiles (256 blocks -> all CUs)
__global__ void k_gemm1(const float* __restrict__ x, const float* __restrict__ W1,
                        float* __restrict__ h) {
    __shared__ float xs[32][33];
    __shared__ float wsm[32][32];
    int tid = threadIdx.x;
    int tc = tid & 7;        // col quad
    int tr = tid >> 3;       // row 0..31
    int rowbase = blockIdx.x * 32;

    float ax = 0.f, ay = 0.f, az = 0.f, aw = 0.f;

    for (int kc = 0; kc < F_IN / 32; ++kc) {
        __syncthreads();
        {
            int pos = tc << 2;
            float4 v = *(const float4*)&x[(size_t)(rowbase + tr) * F_IN + kc * 32 + pos];
            xs[tr][pos + 0] = v.x; xs[tr][pos + 1] = v.y;
            xs[tr][pos + 2] = v.z; xs[tr][pos + 3] = v.w;
            *(float4*)&wsm[tr][pos] = *(const float4*)&W1[(size_t)(kc * 32 + tr) * H1C + pos];
        }
        __syncthreads();
        #pragma unroll
        for (int k = 0; k < 32; ++k) {
            float4 wv = *(const float4*)&wsm[k][tc << 2];
            float xv = xs[tr][k];
            ax += xv * wv.x; ay += xv * wv.y; az += xv * wv.z; aw += xv * wv.w;
        }
    }
    float4 v; v.x = ax; v.y = ay; v.z = az; v.w = aw;
    *(float4*)&h[(size_t)(rowbase + tr) * H1C + (tc << 2)] = v;
}

// gather layer1: one 64-lane wave per dst row; 32 features x 2 slot-parities
__global__ void __launch_bounds__(256)
k_gather1(const int* __restrict__ csr_src, const int* __restrict__ rowptr,
          const float* __restrict__ h, const int* __restrict__ deg,
          float* __restrict__ agg1) {
    int row = blockIdx.x * 4 + (threadIdx.x >> 6);
    int lane = threadIdx.x & 63;
    int f = lane & 31, half = lane >> 5;
    int beg = rowptr[row], end = rowptr[row + 1];
    float acc = 0.0f;
    for (int sl = beg + half; sl < end; sl += 2) {
        int s = csr_src[sl];
        float c = rsqrtf((float)(deg[s] + 1));
        acc = fmaf(h[(s << 5) + f], c, acc);
    }
    acc += __shfl_down(acc, 32, 64);
    if (half == 0)
        agg1[(row << 5) + f] = acc * rsqrtf((float)(deg[row] + 1));
}

// fused: h1 = relu(agg1 + h/(deg+1)) built in LDS, then h1@W2 and h1@W3
__global__ void k_gemm2(const float* __restrict__ agg1, const float* __restrict__ h,
                        const int* __restrict__ deg, const float* __restrict__ W2,
                        const float* __restrict__ W3, float* __restrict__ h2mu,
                        float* __restrict__ h2lv) {
    __shared__ float h1s[8][33];
    __shared__ float w2s[H1C * H2C], w3s[H1C * H2C];
    int tid = threadIdx.x;
    int rb = blockIdx.x * 8;
    for (int i = tid; i < H1C * H2C; i += 256) { w2s[i] = W2[i]; w3s[i] = W3[i]; }
    {
        int r = tid >> 5, c = tid & 31;
        int row = rb + r;
        float d2 = 1.0f / (float)(deg[row] + 1);
        h1s[r][c] = fmaxf(fmaf(h[(row << 5) + c], d2, agg1[(row << 5) + c]), 0.0f);
    }
    __syncthreads();
    int r = tid >> 5, cc = tid & 31, col = cc & 15;
    const float* wsrc = (cc & 16) ? w3s : w2s;
    float acc = 0.0f;
    #pragma unroll
    for (int k = 0; k < H1C; ++k) acc += h1s[r][k] * wsrc[(k << 4) + col];
    int row = rb + r;
    if (cc & 16) h2lv[(row << 4) + col] = acc;
    else         h2mu[(row << 4) + col] = acc;
}

// gather layer2: lanes 0-15 mu, 16-31 lv; halves process alternate slots
__global__ void __launch_bounds__(256)
k_gather2(const int* __restrict__ csr_src, const int* __restrict__ rowptr,
          const float* __restrict__ h2mu, const float* __restrict__ h2lv,
          const int* __restrict__ deg, float* __restrict__ aggmu,
          float* __restrict__ agglv) {
    int row = blockIdx.x * 4 + (threadIdx.x >> 6);
    int lane = threadIdx.x & 63;
    int f = lane & 31, half = lane >> 5;
    int ff = f & 15;
    const float* hsrc = (f < 16) ? h2mu : h2lv;
    int beg = rowptr[row], end = rowptr[row + 1];
    float acc = 0.0f;
    for (int sl = beg + half; sl < end; sl += 2) {
        int s = csr_src[sl];
        float c = rsqrtf((float)(deg[s] + 1));
        acc = fmaf(hsrc[(s << 4) + ff], c, acc);
    }
    acc += __shfl_down(acc, 32, 64);
    if (half == 0) {
        float v = acc * rsqrtf((float)(deg[row] + 1));
        if (f < 16) aggmu[(row << 4) + ff] = v;
        else        agglv[(row << 4) + ff] = v;
    }
}

__global__ void k_zmu(const float* __restrict__ aggmu, const float* __restrict__ agglv,
                      const float* __restrict__ h2mu, const float* __restrict__ h2lv,
                      const int* __restrict__ deg, const float* __restrict__ eps,
                      float* __restrict__ zbuf, float* __restrict__ out,
                      float* __restrict__ kldp) {
    int gid = blockIdx.x * 256 + threadIdx.x;
    int row = gid >> 4;
    float d2 = 1.0f / (float)(deg[row] + 1);
    float m  = fmaf(h2mu[gid], d2, aggmu[gid]);
    float lv = fmaf(h2lv[gid], d2, agglv[gid]);
    float el = __expf(lv);
    float zv = fmaf(eps[gid], el, m);
    zbuf[gid] = zv;
    out[1 + gid] = m;
    float kt = 1.0f + 2.0f * lv - m * m - el * el;
    float bs = block_reduce_sum(kt, 256);
    if (threadIdx.x == 0) kldp[blockIdx.x] = bs;
}

// ---- BCE (identical to round 9/11) ----

#define ADJ_LOAD(t, y0, y1, y2, y3)                                              \
    {                                                                            \
        const int* ap_ = abase + (size_t)(t) * 512;                              \
        y0 = *(const int4*)(ap_);                                                \
        y1 = *(const int4*)(ap_ + N_NODES);                                      \
        y2 = *(const int4*)(ap_ + 2 * N_NODES);                                  \
        y3 = *(const int4*)(ap_ + 3 * N_NODES);                                  \
    }

#define Z_LOAD(t, z0, z1, z2, z3)                                                \
    {                                                                            \
        const float4* zp_ = (const float4*)&z[(size_t)((t) * 512 + tid) * H2C];  \
        z0 = zp_[0]; z1 = zp_[1]; z2 = zp_[2]; z3 = zp_[3];                      \
    }

#define STAGE_WRITE(ZC, z0, z1, z2, z3)                                          \
    {                                                                            \
        ZC[0][tid]  = z0.x; ZC[1][tid]  = z0.y;                                  \
        ZC[2][tid]  = z0.z; ZC[3][tid]  = z0.w;                                  \
        ZC[4][tid]  = z1.x; ZC[5][tid]  = z1.y;                                  \
        ZC[6][tid]  = z1.z; ZC[7][tid]  = z1.w;                                  \
        ZC[8][tid]  = z2.x; ZC[9][tid]  = z2.y;                                  \
        ZC[10][tid] = z2.z; ZC[11][tid] = z2.w;                                  \
        ZC[12][tid] = z3.x; ZC[13][tid] = z3.y;                                  \
        ZC[14][tid] = z3.z; ZC[15][tid] = z3.w;                                  \
    }

#define FMA_TILE(ZC, A)                                                          \
    {                                                                            \
        _Pragma("unroll")                                                        \
        for (int i_ = 0; i_ < 4; ++i_)                                           \
            _Pragma("unroll")                                                    \
            for (int j_ = 0; j_ < 4; ++j_) A[i_][j_] = 0.0f;                     \
        _Pragma("unroll")                                                        \
        for (int k = 0; k < 16; ++k) {                                           \
            float4 c4 = *(const float4*)&ZC[k][tx << 2];                         \
            _Pragma("unroll")                                                    \
            for (int r = 0; r < 4; ++r) {                                        \
                float zv = zr[r][k];                                             \
                A[r][0] += zv * c4.x; A[r][1] += zv * c4.y;                      \
                A[r][2] += zv * c4.z; A[r][3] += zv * c4.w;                      \
            }                                                                    \
        }                                                                        \
    }

#define BCE_APPLY(A, y0, y1, y2, y3)                                             \
    {                                                                            \
        lsum += bce_elem(A[0][0], y0.x) + bce_elem(A[0][1], y0.y)                \
              + bce_elem(A[0][2], y0.z) + bce_elem(A[0][3], y0.w);               \
        lsum += bce_elem(A[1][0], y1.x) + bce_elem(A[1][1], y1.y)                \
              + bce_elem(A[1][2], y1.z) + bce_elem(A[1][3], y1.w);               \
        lsum += bce_elem(A[2][0], y2.x) + bce_elem(A[2][1], y2.y)                \
              + bce_elem(A[2][2], y2.z) + bce_elem(A[2][3], y2.w);               \
        lsum += bce_elem(A[3][0], y3.x) + bce_elem(A[3][1], y3.y)                \
              + bce_elem(A[3][2], y3.z) + bce_elem(A[3][3], y3.w);               \
    }

__global__ void __launch_bounds__(512)
k_bce(const float* __restrict__ z, const int* __restrict__ adj,
      float* __restrict__ part) {
    __shared__ float zcA[16][516];
    __shared__ float zcB[16][516];
    int tid = threadIdx.x;
    int rbase = blockIdx.x << 4;           // 16 rows per block
    int tx = tid & 127, ty = tid >> 7;     // 128 col-groups x 4 row-groups

    // wave-uniform z-rows -> SGPRs (readfirstlane per value)
    float zr[4][16];
    {
        const float* zp = &z[(size_t)(rbase + (ty << 2)) * H2C];
        #pragma unroll
        for (int r = 0; r < 4; ++r)
            #pragma unroll
            for (int k = 0; k < 16; ++k)
                zr[r][k] = rfl(zp[r * 16 + k]);
    }

    const int* abase = adj + (size_t)(rbase + (ty << 2)) * N_NODES + (tx << 2);

    float lsum = 0.0f;
    float4 zN0, zN1, zN2, zN3;
    int4 yC0, yC1, yC2, yC3, yN0, yN1, yN2, yN3;
    float aA[4][4], aB[4][4];

    ADJ_LOAD(0, yC0, yC1, yC2, yC3);
    Z_LOAD(0, zN0, zN1, zN2, zN3);
    STAGE_WRITE(zcA, zN0, zN1, zN2, zN3);
    __syncthreads();

    #pragma unroll 1
    for (int it2 = 0; it2 < 8; ++it2) {
        const int t = 2 * it2;
        ADJ_LOAD(t + 1, yN0, yN1, yN2, yN3);
        Z_LOAD(t + 1, zN0, zN1, zN2, zN3);
        FMA_TILE(zcA, aA);
        BCE_APPLY(aA, yC0, yC1, yC2, yC3);
        STAGE_WRITE(zcB, zN0, zN1, zN2, zN3);
        __syncthreads();

        if (it2 < 7) {
            ADJ_LOAD(t + 2, yC0, yC1, yC2, yC3);
            Z_LOAD(t + 2, zN0, zN1, zN2, zN3);
        }
        FMA_TILE(zcB, aB);
        BCE_APPLY(aB, yN0, yN1, yN2, yN3);
        if (it2 < 7) {
            STAGE_WRITE(zcA, zN0, zN1, zN2, zN3);
            __syncthreads();
        }
    }

    float bs = block_reduce_sum(lsum, 512);
    if (tid == 0) part[blockIdx.x] = bs;
}

__global__ void k_final(const float* __restrict__ part, const float* __restrict__ kldp,
                        const float* __restrict__ norm, float* __restrict__ out) {
    double s = 0.0, k = 0.0;
    for (int i = threadIdx.x; i < 512; i += 256) s += (double)part[i];
    for (int i = threadIdx.x; i < 512; i += 256) k += (double)kldp[i];
    #pragma unroll
    for (int off = 32; off; off >>= 1) {
        s += __shfl_down(s, off, 64);
        k += __shfl_down(k, off, 64);
    }
    __shared__ double ss[4], kk[4];
    int lane = threadIdx.x & 63, wid = threadIdx.x >> 6;
    if (lane == 0) { ss[wid] = s; kk[wid] = k; }
    __syncthreads();
    if (threadIdx.x == 0) {
        double st = ss[0] + ss[1] + ss[2] + ss[3];
        double kt = kk[0] + kk[1] + kk[2] + kk[3];
        double bce = st / ((double)N_NODES * (double)N_NODES);
        double kld = (-0.5 / (double)N_NODES) * (kt / (double)N_NODES);
        out[0] = (float)((double)norm[0] * bce + kld);
    }
}

// ---------------- launch ----------------

extern "C" void kernel_launch(void* const* d_in, const int* in_sizes, int n_in,
                              void* d_out, int out_size, void* d_ws, size_t ws_size,
                              hipStream_t stream) {
    const float* x    = (const float*)d_in[0];
    const int*   ei   = (const int*)d_in[1];
    const int*   adj  = (const int*)d_in[2];
    const float* eps  = (const float*)d_in[3];
    const float* norm = (const float*)d_in[4];
    const float* W1   = (const float*)d_in[5];
    const float* W2   = (const float*)d_in[6];
    const float* W3   = (const float*)d_in[7];
    float* out = (float*)d_out;
    char*  ws  = (char*)d_ws;

    const int* src = ei;
    const int* dst = ei + N_EDGES;

    int*   deg     = (int*)  (ws + 0);        // 32 KB
    int*   cursor  = (int*)  (ws + 32768);    // 32 KB (contiguous with deg)
    int*   rowptr  = (int*)  (ws + 65536);    // 8193 i32
    int*   csr_src = (int*)  (ws + 102400);   // 512 KB
    float* h       = (float*)(ws + 626688);   // 1 MB
    float* agg1    = (float*)(ws + 1675264);  // 1 MB
    float* h2mu    = (float*)(ws + 2723840);  // 512 KB
    float* h2lv    = (float*)(ws + 3248128);  // 512 KB
    float* aggmu   = (float*)(ws + 3772416);  // 512 KB
    float* agglv   = (float*)(ws + 4296704);  // 512 KB
    float* zbuf    = (float*)(ws + 4820992);  // 512 KB
    float* part    = (float*)(ws + 5345280);  // 512 f32
    float* kldp    = (float*)(ws + 5347328);  // 512 f32
    float* part2   = (float*)(ws + 5349376);  // 512 f32 (probe sink)
    int*   sink    = (int*)  (ws + 5353472);  // 2 MB (probe sink)

    // ---- real chain (byte-identical to round 11) ----
    k_init<<<16, 256, 0, stream>>>((float4*)deg);
    k_deg<<<N_EDGES / 256, 256, 0, stream>>>(dst, deg);
    k_scan<<<1, 256, 0, stream>>>(deg, rowptr);
    k_fill<<<N_EDGES / 256, 256, 0, stream>>>(src, dst, rowptr, cursor, csr_src);
    k_gemm1<<<N_NODES / 32, 256, 0, stream>>>(x, W1, h);
    k_gather1<<<N_NODES / 4, 256, 0, stream>>>(csr_src, rowptr, h, deg, agg1);
    k_gemm2<<<N_NODES / 8, 256, 0, stream>>>(agg1, h, deg, W2, W3, h2mu, h2lv);
    k_gather2<<<N_NODES / 4, 256, 0, stream>>>(csr_src, rowptr, h2mu, h2lv, deg, aggmu, agglv);
    k_zmu<<<(N_NODES * H2C) / 256, 256, 0, stream>>>(aggmu, agglv, h2mu, h2lv, deg, eps, zbuf, out, kldp);
    k_bce<<<512, 512, 0, stream>>>(zbuf, adj, part);
    k_final<<<1, 256, 0, stream>>>(part, kldp, norm, out);

    // ---- PROBES (scratch-only writes; T = base + 2*T_stream + T_bce) ----
    k_stream<<<2048, 256, 0, stream>>>((const int4*)adj, sink);
    k_stream<<<2048, 256, 0, stream>>>((const int4*)adj, sink);
    k_bce<<<512, 512, 0, stream>>>(zbuf, adj, part2);
}

// Round 13
// 154.004 us; speedup vs baseline: 2.5718x; 2.5718x over previous
//
#include <hip/hip_runtime.h>
#include <cstdint>
#include <cstddef>

#define N_NODES 8192
#define N_EDGES 131072
#define F_IN    512
#define H1C     32
#define H2C     16

// ---------------- helpers ----------------

__device__ __forceinline__ float block_reduce_sum(float v, int nthreads) {
    #pragma unroll
    for (int off = 32; off; off >>= 1) v += __shfl_down(v, off, 64);
    __shared__ float sred[16];
    int lane = threadIdx.x & 63, wid = threadIdx.x >> 6;
    if (lane == 0) sred[wid] = v;
    __syncthreads();
    float s = 0.0f;
    if (threadIdx.x == 0) {
        int nw = nthreads >> 6;
        for (int i = 0; i < nw; ++i) s += sred[i];
    }
    return s;
}

// POS_WEIGHT=10: y=1 -> 10*softplus(-l); y=0 -> softplus(l).
// Branch-free: sp(l) = lse + relu(l);  val = sp(l)*(1+9y) - 10*y*l
__device__ __forceinline__ float bce_elem(float l, int y) {
    float lse = __logf(1.0f + __expf(-fabsf(l)));
    float sp  = lse + fmaxf(l, 0.0f);
    float w   = (float)y;
    return fmaf(sp, fmaf(9.0f, w, 1.0f), -10.0f * w * l);
}

// force a wave-uniform float into an SGPR
__device__ __forceinline__ float rfl(float x) {
    return __int_as_float(__builtin_amdgcn_readfirstlane(__float_as_int(x)));
}

// ---------------- kernels ----------------

// zero deg + cursor (contiguous 64 KB = 4096 float4)
__global__ void k_init(float4* __restrict__ p) {
    int gid = blockIdx.x * 256 + threadIdx.x;
    float4 zz = {0.0f, 0.0f, 0.0f, 0.0f};
    p[gid] = zz;
}

__global__ void k_deg(const int* __restrict__ dst, int* __restrict__ deg) {
    int e = blockIdx.x * 256 + threadIdx.x;
    if (e < N_EDGES) atomicAdd(&deg[dst[e]], 1);
}

// exclusive scan of deg[8192] -> rowptr[8193]; single block of 256 threads
__global__ void k_scan(const int* __restrict__ deg, int* __restrict__ rowptr) {
    __shared__ int part[256];
    __shared__ int pref[257];
    int t = threadIdx.x;
    int base = t * 32;
    int vals[32];
    int s = 0;
    #pragma unroll
    for (int j = 0; j < 32; ++j) { vals[j] = deg[base + j]; s += vals[j]; }
    part[t] = s;
    __syncthreads();
    if (t == 0) {
        int run = 0;
        for (int i = 0; i < 256; ++i) { pref[i] = run; run += part[i]; }
        pref[256] = run;
    }
    __syncthreads();
    int run = pref[t];
    #pragma unroll
    for (int j = 0; j < 32; ++j) { rowptr[base + j] = run; run += vals[j]; }
    if (t == 255) rowptr[8192] = pref[256];
}

// bucket edges by dst: csr_src[slot] = src[e]  (131K int atomics on cursor)
__global__ void k_fill(const int* __restrict__ src, const int* __restrict__ dst,
                       const int* __restrict__ rowptr, int* __restrict__ cursor,
                       int* __restrict__ csr_src) {
    int e = blockIdx.x * 256 + threadIdx.x;
    int d = dst[e];
    int slot = rowptr[d] + atomicAdd(&cursor[d], 1);
    csr_src[slot] = src[e];
}

// h = x @ W1 : [8192,512] x [512,32], 32-row tiles (256 blocks -> all CUs)
__global__ void k_gemm1(const float* __restrict__ x, const float* __restrict__ W1,
                        float* __restrict__ h) {
    __shared__ float xs[32][33];
    __shared__ float wsm[32][32];
    int tid = threadIdx.x;
    int tc = tid & 7;        // col quad
    int tr = tid >> 3;       // row 0..31
    int rowbase = blockIdx.x * 32;

    float ax = 0.f, ay = 0.f, az = 0.f, aw = 0.f;

    for (int kc = 0; kc < F_IN / 32; ++kc) {
        __syncthreads();
        {
            int pos = tc << 2;
            float4 v = *(const float4*)&x[(size_t)(rowbase + tr) * F_IN + kc * 32 + pos];
            xs[tr][pos + 0] = v.x; xs[tr][pos + 1] = v.y;
            xs[tr][pos + 2] = v.z; xs[tr][pos + 3] = v.w;
            *(float4*)&wsm[tr][pos] = *(const float4*)&W1[(size_t)(kc * 32 + tr) * H1C + pos];
        }
        __syncthreads();
        #pragma unroll
        for (int k = 0; k < 32; ++k) {
            float4 wv = *(const float4*)&wsm[k][tc << 2];
            float xv = xs[tr][k];
            ax += xv * wv.x; ay += xv * wv.y; az += xv * wv.z; aw += xv * wv.w;
        }
    }
    float4 v; v.x = ax; v.y = ay; v.z = az; v.w = aw;
    *(float4*)&h[(size_t)(rowbase + tr) * H1C + (tc << 2)] = v;
}

// gather layer1: one 64-lane wave per dst row; 32 features x 2 slot-parities
__global__ void __launch_bounds__(256)
k_gather1(const int* __restrict__ csr_src, const int* __restrict__ rowptr,
          const float* __restrict__ h, const int* __restrict__ deg,
          float* __restrict__ agg1) {
    int row = blockIdx.x * 4 + (threadIdx.x >> 6);
    int lane = threadIdx.x & 63;
    int f = lane & 31, half = lane >> 5;
    int beg = rowptr[row], end = rowptr[row + 1];
    float acc = 0.0f;
    for (int sl = beg + half; sl < end; sl += 2) {
        int s = csr_src[sl];
        float c = rsqrtf((float)(deg[s] + 1));
        acc = fmaf(h[(s << 5) + f], c, acc);
    }
    acc += __shfl_down(acc, 32, 64);
    if (half == 0)
        agg1[(row << 5) + f] = acc * rsqrtf((float)(deg[row] + 1));
}

// fused: h1 = relu(agg1 + h/(deg+1)) built in LDS, then h1@W2 and h1@W3
__global__ void k_gemm2(const float* __restrict__ agg1, const float* __restrict__ h,
                        const int* __restrict__ deg, const float* __restrict__ W2,
                        const float* __restrict__ W3, float* __restrict__ h2mu,
                        float* __restrict__ h2lv) {
    __shared__ float h1s[8][33];
    __shared__ float w2s[H1C * H2C], w3s[H1C * H2C];
    int tid = threadIdx.x;
    int rb = blockIdx.x * 8;
    for (int i = tid; i < H1C * H2C; i += 256) { w2s[i] = W2[i]; w3s[i] = W3[i]; }
    {
        int r = tid >> 5, c = tid & 31;
        int row = rb + r;
        float d2 = 1.0f / (float)(deg[row] + 1);
        h1s[r][c] = fmaxf(fmaf(h[(row << 5) + c], d2, agg1[(row << 5) + c]), 0.0f);
    }
    __syncthreads();
    int r = tid >> 5, cc = tid & 31, col = cc & 15;
    const float* wsrc = (cc & 16) ? w3s : w2s;
    float acc = 0.0f;
    #pragma unroll
    for (int k = 0; k < H1C; ++k) acc += h1s[r][k] * wsrc[(k << 4) + col];
    int row = rb + r;
    if (cc & 16) h2lv[(row << 4) + col] = acc;
    else         h2mu[(row << 4) + col] = acc;
}

// gather layer2: lanes 0-15 mu, 16-31 lv; halves process alternate slots
__global__ void __launch_bounds__(256)
k_gather2(const int* __restrict__ csr_src, const int* __restrict__ rowptr,
          const float* __restrict__ h2mu, const float* __restrict__ h2lv,
          const int* __restrict__ deg, float* __restrict__ aggmu,
          float* __restrict__ agglv) {
    int row = blockIdx.x * 4 + (threadIdx.x >> 6);
    int lane = threadIdx.x & 63;
    int f = lane & 31, half = lane >> 5;
    int ff = f & 15;
    const float* hsrc = (f < 16) ? h2mu : h2lv;
    int beg = rowptr[row], end = rowptr[row + 1];
    float acc = 0.0f;
    for (int sl = beg + half; sl < end; sl += 2) {
        int s = csr_src[sl];
        float c = rsqrtf((float)(deg[s] + 1));
        acc = fmaf(hsrc[(s << 4) + ff], c, acc);
    }
    acc += __shfl_down(acc, 32, 64);
    if (half == 0) {
        float v = acc * rsqrtf((float)(deg[row] + 1));
        if (f < 16) aggmu[(row << 4) + ff] = v;
        else        agglv[(row << 4) + ff] = v;
    }
}

__global__ void k_zmu(const float* __restrict__ aggmu, const float* __restrict__ agglv,
                      const float* __restrict__ h2mu, const float* __restrict__ h2lv,
                      const int* __restrict__ deg, const float* __restrict__ eps,
                      float* __restrict__ zbuf, float* __restrict__ out,
                      float* __restrict__ kldp) {
    int gid = blockIdx.x * 256 + threadIdx.x;
    int row = gid >> 4;
    float d2 = 1.0f / (float)(deg[row] + 1);
    float m  = fmaf(h2mu[gid], d2, aggmu[gid]);
    float lv = fmaf(h2lv[gid], d2, agglv[gid]);
    float el = __expf(lv);
    float zv = fmaf(eps[gid], el, m);
    zbuf[gid] = zv;
    out[1 + gid] = m;
    float kt = 1.0f + 2.0f * lv - m * m - el * el;
    float bs = block_reduce_sum(kt, 256);
    if (threadIdx.x == 0) kldp[blockIdx.x] = bs;
}

// ---- BCE v2: barrier-free, k_stream-shaped. 2048 blocks x 256 threads.
// band = blockIdx&7 -> 4 FIXED cols/thread (zc[4][16] loaded once, 256B
// contiguous; band==XCD id so zc slab is XCD-L2-resident). rblk = blockIdx>>3
// -> 32 rows, iterated in 8 fully-unrolled steps of 4 wave-uniform rows
// (zr via readfirstlane, L1 broadcast). Per step: 4 coalesced int4 adj loads
// (1KB/wave/row), 256 FMA, 16 bce. NO LDS staging, NO __syncthreads in the
// hot path -> loads from consecutive steps stay in flight (k_stream regime).
__global__ void __launch_bounds__(256)
k_bce(const float* __restrict__ z, const int* __restrict__ adj,
      float* __restrict__ part) {
    int tid = threadIdx.x;
    int band = blockIdx.x & 7;
    int rblk = blockIdx.x >> 3;
    int col0 = (band << 10) + (tid << 2);
    int row0 = rblk << 5;

    // zc: this thread's 4 cols x 16 k (256B contiguous, loaded once)
    float zc[4][16];
    {
        const float4* zp = (const float4*)&z[(size_t)col0 * H2C];
        #pragma unroll
        for (int c = 0; c < 4; ++c)
            #pragma unroll
            for (int q = 0; q < 4; ++q) {
                float4 v = zp[c * 4 + q];
                zc[c][q * 4 + 0] = v.x; zc[c][q * 4 + 1] = v.y;
                zc[c][q * 4 + 2] = v.z; zc[c][q * 4 + 3] = v.w;
            }
    }

    float lsum = 0.0f;
    #pragma unroll
    for (int step = 0; step < 8; ++step) {
        int r0 = row0 + (step << 2);
        const int* ap = adj + (size_t)r0 * N_NODES + col0;
        int4 y0 = *(const int4*)(ap);
        int4 y1 = *(const int4*)(ap + N_NODES);
        int4 y2 = *(const int4*)(ap + 2 * N_NODES);
        int4 y3 = *(const int4*)(ap + 3 * N_NODES);

        // wave-uniform z rows -> SGPRs (L1-broadcast loads + readfirstlane)
        float zr[4][16];
        {
            const float* zp = &z[(size_t)r0 * H2C];
            #pragma unroll
            for (int r = 0; r < 4; ++r)
                #pragma unroll
                for (int k = 0; k < 16; ++k)
                    zr[r][k] = rfl(zp[r * 16 + k]);
        }

        float a[4][4];
        #pragma unroll
        for (int r = 0; r < 4; ++r)
            #pragma unroll
            for (int c = 0; c < 4; ++c) a[r][c] = 0.0f;
        #pragma unroll
        for (int k = 0; k < 16; ++k) {
            #pragma unroll
            for (int r = 0; r < 4; ++r) {
                float zv = zr[r][k];
                a[r][0] = fmaf(zv, zc[0][k], a[r][0]);
                a[r][1] = fmaf(zv, zc[1][k], a[r][1]);
                a[r][2] = fmaf(zv, zc[2][k], a[r][2]);
                a[r][3] = fmaf(zv, zc[3][k], a[r][3]);
            }
        }
        lsum += bce_elem(a[0][0], y0.x) + bce_elem(a[0][1], y0.y)
              + bce_elem(a[0][2], y0.z) + bce_elem(a[0][3], y0.w);
        lsum += bce_elem(a[1][0], y1.x) + bce_elem(a[1][1], y1.y)
              + bce_elem(a[1][2], y1.z) + bce_elem(a[1][3], y1.w);
        lsum += bce_elem(a[2][0], y2.x) + bce_elem(a[2][1], y2.y)
              + bce_elem(a[2][2], y2.z) + bce_elem(a[2][3], y2.w);
        lsum += bce_elem(a[3][0], y3.x) + bce_elem(a[3][1], y3.y)
              + bce_elem(a[3][2], y3.z) + bce_elem(a[3][3], y3.w);
    }

    float bs = block_reduce_sum(lsum, 256);
    if (tid == 0) part[blockIdx.x] = bs;
}

__global__ void k_final(const float* __restrict__ part, const float* __restrict__ kldp,
                        const float* __restrict__ norm, float* __restrict__ out) {
    double s = 0.0, k = 0.0;
    for (int i = threadIdx.x; i < 2048; i += 256) s += (double)part[i];
    for (int i = threadIdx.x; i < 512; i += 256) k += (double)kldp[i];
    #pragma unroll
    for (int off = 32; off; off >>= 1) {
        s += __shfl_down(s, off, 64);
        k += __shfl_down(k, off, 64);
    }
    __shared__ double ss[4], kk[4];
    int lane = threadIdx.x & 63, wid = threadIdx.x >> 6;
    if (lane == 0) { ss[wid] = s; kk[wid] = k; }
    __syncthreads();
    if (threadIdx.x == 0) {
        double st = ss[0] + ss[1] + ss[2] + ss[3];
        double kt = kk[0] + kk[1] + kk[2] + kk[3];
        double bce = st / ((double)N_NODES * (double)N_NODES);
        double kld = (-0.5 / (double)N_NODES) * (kt / (double)N_NODES);
        out[0] = (float)((double)norm[0] * bce + kld);
    }
}

// ---------------- launch ----------------

extern "C" void kernel_launch(void* const* d_in, const int* in_sizes, int n_in,
                              void* d_out, int out_size, void* d_ws, size_t ws_size,
                              hipStream_t stream) {
    const float* x    = (const float*)d_in[0];
    const int*   ei   = (const int*)d_in[1];
    const int*   adj  = (const int*)d_in[2];
    const float* eps  = (const float*)d_in[3];
    const float* norm = (const float*)d_in[4];
    const float* W1   = (const float*)d_in[5];
    const float* W2   = (const float*)d_in[6];
    const float* W3   = (const float*)d_in[7];
    float* out = (float*)d_out;
    char*  ws  = (char*)d_ws;

    const int* src = ei;
    const int* dst = ei + N_EDGES;

    int*   deg     = (int*)  (ws + 0);        // 32 KB
    int*   cursor  = (int*)  (ws + 32768);    // 32 KB (contiguous with deg)
    int*   rowptr  = (int*)  (ws + 65536);    // 8193 i32
    int*   csr_src = (int*)  (ws + 102400);   // 512 KB
    float* h       = (float*)(ws + 626688);   // 1 MB
    float* agg1    = (float*)(ws + 1675264);  // 1 MB
    float* h2mu    = (float*)(ws + 2723840);  // 512 KB
    float* h2lv    = (float*)(ws + 3248128);  // 512 KB
    float* aggmu   = (float*)(ws + 3772416);  // 512 KB
    float* agglv   = (float*)(ws + 4296704);  // 512 KB
    float* zbuf    = (float*)(ws + 4820992);  // 512 KB
    float* part    = (float*)(ws + 5345280);  // 2048 f32
    float* kldp    = (float*)(ws + 5353472);  // 512 f32

    k_init<<<16, 256, 0, stream>>>((float4*)deg);
    k_deg<<<N_EDGES / 256, 256, 0, stream>>>(dst, deg);
    k_scan<<<1, 256, 0, stream>>>(deg, rowptr);
    k_fill<<<N_EDGES / 256, 256, 0, stream>>>(src, dst, rowptr, cursor, csr_src);
    k_gemm1<<<N_NODES / 32, 256, 0, stream>>>(x, W1, h);
    k_gather1<<<N_NODES / 4, 256, 0, stream>>>(csr_src, rowptr, h, deg, agg1);
    k_gemm2<<<N_NODES / 8, 256, 0, stream>>>(agg1, h, deg, W2, W3, h2mu, h2lv);
    k_gather2<<<N_NODES / 4, 256, 0, stream>>>(csr_src, rowptr, h2mu, h2lv, deg, aggmu, agglv);
    k_zmu<<<(N_NODES * H2C) / 256, 256, 0, stream>>>(aggmu, agglv, h2mu, h2lv, deg, eps, zbuf, out, kldp);
    k_bce<<<2048, 256, 0, stream>>>(zbuf, adj, part);
    k_final<<<1, 256, 0, stream>>>(part, kldp, norm, out);
}

// Round 14
// 146.267 us; speedup vs baseline: 2.7079x; 1.0529x over previous
//
#include <hip/hip_runtime.h>
#include <cstdint>
#include <cstddef>

#define N_NODES 8192
#define N_EDGES 131072
#define F_IN    512
#define H1C     32
#define H2C     16

// ---------------- helpers ----------------

__device__ __forceinline__ float block_reduce_sum(float v, int nthreads) {
    #pragma unroll
    for (int off = 32; off; off >>= 1) v += __shfl_down(v, off, 64);
    __shared__ float sred[16];
    int lane = threadIdx.x & 63, wid = threadIdx.x >> 6;
    if (lane == 0) sred[wid] = v;
    __syncthreads();
    float s = 0.0f;
    if (threadIdx.x == 0) {
        int nw = nthreads >> 6;
        for (int i = 0; i < nw; ++i) s += sred[i];
    }
    return s;
}

// POS_WEIGHT=10: y=1 -> 10*softplus(-l); y=0 -> softplus(l).
// Branch-free: sp(l) = lse + relu(l);  val = sp(l)*(1+9y) - 10*y*l
__device__ __forceinline__ float bce_elem(float l, int y) {
    float lse = __logf(1.0f + __expf(-fabsf(l)));
    float sp  = lse + fmaxf(l, 0.0f);
    float w   = (float)y;
    return fmaf(sp, fmaf(9.0f, w, 1.0f), -10.0f * w * l);
}

// force a wave-uniform float into an SGPR
__device__ __forceinline__ float rfl(float x) {
    return __int_as_float(__builtin_amdgcn_readfirstlane(__float_as_int(x)));
}

// ---------------- kernels ----------------

// zero deg + cursor (contiguous 64 KB = 4096 float4)
__global__ void k_init(float4* __restrict__ p) {
    int gid = blockIdx.x * 256 + threadIdx.x;
    float4 zz = {0.0f, 0.0f, 0.0f, 0.0f};
    p[gid] = zz;
}

__global__ void k_deg(const int* __restrict__ dst, int* __restrict__ deg) {
    int e = blockIdx.x * 256 + threadIdx.x;
    if (e < N_EDGES) atomicAdd(&deg[dst[e]], 1);
}

// exclusive scan of deg[8192] -> rowptr[8193], plus dinv[i]=rsqrt(deg+1).
// Parallel: per-thread 32-chunk sum -> wave shuffle scan -> cross-wave via LDS.
__global__ void k_scan(const int* __restrict__ deg, int* __restrict__ rowptr,
                       float* __restrict__ dinv) {
    int t = threadIdx.x;           // 256
    int base = t * 32;
    int vals[32];
    int s = 0;
    #pragma unroll
    for (int j = 0; j < 32; ++j) {
        vals[j] = deg[base + j];
        s += vals[j];
        dinv[base + j] = rsqrtf((float)(vals[j] + 1));
    }
    int lane = t & 63, wid = t >> 6;
    int inc = s;
    #pragma unroll
    for (int off = 1; off < 64; off <<= 1) {
        int n = __shfl_up(inc, off, 64);
        if (lane >= off) inc += n;
    }
    __shared__ int wsum[4];
    if (lane == 63) wsum[wid] = inc;
    __syncthreads();
    int woff = 0;
    for (int i = 0; i < wid; ++i) woff += wsum[i];
    int run = woff + inc - s;      // exclusive prefix for this thread's chunk
    #pragma unroll
    for (int j = 0; j < 32; ++j) { rowptr[base + j] = run; run += vals[j]; }
    if (t == 255) rowptr[8192] = run;
}

// bucket edges by dst: csr_src/csr_coef (coef precomputed -> one less chained
// load in the gather inner loop)
__global__ void k_fill(const int* __restrict__ src, const int* __restrict__ dst,
                       const int* __restrict__ rowptr, const float* __restrict__ dinv,
                       int* __restrict__ cursor, int* __restrict__ csr_src,
                       float* __restrict__ csr_coef) {
    int e = blockIdx.x * 256 + threadIdx.x;
    int d = dst[e], sv = src[e];
    int slot = rowptr[d] + atomicAdd(&cursor[d], 1);
    csr_src[slot] = sv;
    csr_coef[slot] = dinv[sv];
}

// h = x @ W1, BARRIER-FREE: W1 (64KB) staged in LDS once, then each thread
// streams its x row from global (L1 dedups the 8 lanes sharing a row) with
// zero barriers in the k-loop. Old version: 16 barrier-fenced phases at
// 1 wave/SIMD -> every vmcnt(0) drain exposed.
__global__ void __launch_bounds__(256)
k_gemm1(const float* __restrict__ x, const float* __restrict__ W1,
        float* __restrict__ h) {
    __shared__ float wsm[F_IN][H1C];   // 64 KB
    int tid = threadIdx.x;
    {
        float4* wd = (float4*)wsm;
        const float4* wsrc = (const float4*)W1;
        #pragma unroll
        for (int i = 0; i < 16; ++i) wd[tid + i * 256] = wsrc[tid + i * 256];
    }
    __syncthreads();

    int row = (blockIdx.x << 5) + (tid >> 3);
    int c4 = (tid & 7) << 2;
    const float4* xp = (const float4*)&x[(size_t)row * F_IN];

    float ax = 0.f, ay = 0.f, az = 0.f, aw = 0.f;
    #pragma unroll 8
    for (int k4 = 0; k4 < F_IN / 4; ++k4) {
        float4 xv = xp[k4];
        float4 w0 = *(const float4*)&wsm[k4 * 4 + 0][c4];
        float4 w1 = *(const float4*)&wsm[k4 * 4 + 1][c4];
        float4 w2 = *(const float4*)&wsm[k4 * 4 + 2][c4];
        float4 w3 = *(const float4*)&wsm[k4 * 4 + 3][c4];
        ax = fmaf(xv.x, w0.x, ax); ay = fmaf(xv.x, w0.y, ay);
        az = fmaf(xv.x, w0.z, az); aw = fmaf(xv.x, w0.w, aw);
        ax = fmaf(xv.y, w1.x, ax); ay = fmaf(xv.y, w1.y, ay);
        az = fmaf(xv.y, w1.z, az); aw = fmaf(xv.y, w1.w, aw);
        ax = fmaf(xv.z, w2.x, ax); ay = fmaf(xv.z, w2.y, ay);
        az = fmaf(xv.z, w2.z, az); aw = fmaf(xv.z, w2.w, aw);
        ax = fmaf(xv.w, w3.x, ax); ay = fmaf(xv.w, w3.y, ay);
        az = fmaf(xv.w, w3.z, az); aw = fmaf(xv.w, w3.w, aw);
    }
    float4 v; v.x = ax; v.y = ay; v.z = az; v.w = aw;
    *(float4*)&h[(size_t)row * H1C + c4] = v;
}

// gather layer1: one 64-lane wave per dst row; 32 features x 2 slot-parities.
// csr_coef read in parallel with csr_src (no chained deg load).
__global__ void __launch_bounds__(256)
k_gather1(const int* __restrict__ csr_src, const float* __restrict__ csr_coef,
          const int* __restrict__ rowptr, const float* __restrict__ h,
          const float* __restrict__ dinv, float* __restrict__ agg1) {
    int row = blockIdx.x * 4 + (threadIdx.x >> 6);
    int lane = threadIdx.x & 63;
    int f = lane & 31, half = lane >> 5;
    int beg = rowptr[row], end = rowptr[row + 1];
    float acc = 0.0f;
    for (int sl = beg + half; sl < end; sl += 2) {
        int s = csr_src[sl];
        float c = csr_coef[sl];
        acc = fmaf(h[(s << 5) + f], c, acc);
    }
    acc += __shfl_down(acc, 32, 64);
    if (half == 0)
        agg1[(row << 5) + f] = acc * dinv[row];
}

// fused: h1 = relu(agg1 + h*dinv^2) built in LDS, then h1@W2 and h1@W3
__global__ void k_gemm2(const float* __restrict__ agg1, const float* __restrict__ h,
                        const float* __restrict__ dinv, const float* __restrict__ W2,
                        const float* __restrict__ W3, float* __restrict__ h2mu,
                        float* __restrict__ h2lv) {
    __shared__ float h1s[8][33];
    __shared__ float w2s[H1C * H2C], w3s[H1C * H2C];
    int tid = threadIdx.x;
    int rb = blockIdx.x * 8;
    for (int i = tid; i < H1C * H2C; i += 256) { w2s[i] = W2[i]; w3s[i] = W3[i]; }
    {
        int r = tid >> 5, c = tid & 31;
        int row = rb + r;
        float di = dinv[row], d2 = di * di;
        h1s[r][c] = fmaxf(fmaf(h[(row << 5) + c], d2, agg1[(row << 5) + c]), 0.0f);
    }
    __syncthreads();
    int r = tid >> 5, cc = tid & 31, col = cc & 15;
    const float* wsrc = (cc & 16) ? w3s : w2s;
    float acc = 0.0f;
    #pragma unroll
    for (int k = 0; k < H1C; ++k) acc += h1s[r][k] * wsrc[(k << 4) + col];
    int row = rb + r;
    if (cc & 16) h2lv[(row << 4) + col] = acc;
    else         h2mu[(row << 4) + col] = acc;
}

// gather layer2: lanes 0-15 mu, 16-31 lv; halves process alternate slots
__global__ void __launch_bounds__(256)
k_gather2(const int* __restrict__ csr_src, const float* __restrict__ csr_coef,
          const int* __restrict__ rowptr, const float* __restrict__ h2mu,
          const float* __restrict__ h2lv, const float* __restrict__ dinv,
          float* __restrict__ aggmu, float* __restrict__ agglv) {
    int row = blockIdx.x * 4 + (threadIdx.x >> 6);
    int lane = threadIdx.x & 63;
    int f = lane & 31, half = lane >> 5;
    int ff = f & 15;
    const float* hsrc = (f < 16) ? h2mu : h2lv;
    int beg = rowptr[row], end = rowptr[row + 1];
    float acc = 0.0f;
    for (int sl = beg + half; sl < end; sl += 2) {
        int s = csr_src[sl];
        float c = csr_coef[sl];
        acc = fmaf(hsrc[(s << 4) + ff], c, acc);
    }
    acc += __shfl_down(acc, 32, 64);
    if (half == 0) {
        float v = acc * dinv[row];
        if (f < 16) aggmu[(row << 4) + ff] = v;
        else        agglv[(row << 4) + ff] = v;
    }
}

__global__ void k_zmu(const float* __restrict__ aggmu, const float* __restrict__ agglv,
                      const float* __restrict__ h2mu, const float* __restrict__ h2lv,
                      const float* __restrict__ dinv, const float* __restrict__ eps,
                      float* __restrict__ zbuf, float* __restrict__ out,
                      float* __restrict__ kldp) {
    int gid = blockIdx.x * 256 + threadIdx.x;
    int row = gid >> 4;
    float di = dinv[row], d2 = di * di;
    float m  = fmaf(h2mu[gid], d2, aggmu[gid]);
    float lv = fmaf(h2lv[gid], d2, agglv[gid]);
    float el = __expf(lv);
    float zv = fmaf(eps[gid], el, m);
    zbuf[gid] = zv;
    out[1 + gid] = m;
    float kt = 1.0f + 2.0f * lv - m * m - el * el;
    float bs = block_reduce_sum(kt, 256);
    if (threadIdx.x == 0) kldp[blockIdx.x] = bs;
}

// ---- BCE v2.1: barrier-free (r13 structure); zr loaded as 16 float4 per
// step (was 64 scalar loads) then readfirstlane'd into SGPRs.
__global__ void __launch_bounds__(256)
k_bce(const float* __restrict__ z, const int* __restrict__ adj,
      float* __restrict__ part) {
    int tid = threadIdx.x;
    int band = blockIdx.x & 7;
    int rblk = blockIdx.x >> 3;
    int col0 = (band << 10) + (tid << 2);
    int row0 = rblk << 5;

    // zc: this thread's 4 cols x 16 k (256B contiguous, loaded once)
    float zc[4][16];
    {
        const float4* zp = (const float4*)&z[(size_t)col0 * H2C];
        #pragma unroll
        for (int c = 0; c < 4; ++c)
            #pragma unroll
            for (int q = 0; q < 4; ++q) {
                float4 v = zp[c * 4 + q];
                zc[c][q * 4 + 0] = v.x; zc[c][q * 4 + 1] = v.y;
                zc[c][q * 4 + 2] = v.z; zc[c][q * 4 + 3] = v.w;
            }
    }

    float lsum = 0.0f;
    #pragma unroll
    for (int step = 0; step < 8; ++step) {
        int r0 = row0 + (step << 2);
        const int* ap = adj + (size_t)r0 * N_NODES + col0;
        int4 y0 = *(const int4*)(ap);
        int4 y1 = *(const int4*)(ap + N_NODES);
        int4 y2 = *(const int4*)(ap + 2 * N_NODES);
        int4 y3 = *(const int4*)(ap + 3 * N_NODES);

        // wave-uniform z rows: 16 float4 L1-broadcast loads -> SGPRs
        float zr[4][16];
        {
            const float4* zp = (const float4*)&z[(size_t)r0 * H2C];
            #pragma unroll
            for (int q = 0; q < 16; ++q) {
                float4 v = zp[q];
                int r = q >> 2, qq = (q & 3) << 2;
                zr[r][qq + 0] = rfl(v.x); zr[r][qq + 1] = rfl(v.y);
                zr[r][qq + 2] = rfl(v.z); zr[r][qq + 3] = rfl(v.w);
            }
        }

        float a[4][4];
        #pragma unroll
        for (int r = 0; r < 4; ++r)
            #pragma unroll
            for (int c = 0; c < 4; ++c) a[r][c] = 0.0f;
        #pragma unroll
        for (int k = 0; k < 16; ++k) {
            #pragma unroll
            for (int r = 0; r < 4; ++r) {
                float zv = zr[r][k];
                a[r][0] = fmaf(zv, zc[0][k], a[r][0]);
                a[r][1] = fmaf(zv, zc[1][k], a[r][1]);
                a[r][2] = fmaf(zv, zc[2][k], a[r][2]);
                a[r][3] = fmaf(zv, zc[3][k], a[r][3]);
            }
        }
        lsum += bce_elem(a[0][0], y0.x) + bce_elem(a[0][1], y0.y)
              + bce_elem(a[0][2], y0.z) + bce_elem(a[0][3], y0.w);
        lsum += bce_elem(a[1][0], y1.x) + bce_elem(a[1][1], y1.y)
              + bce_elem(a[1][2], y1.z) + bce_elem(a[1][3], y1.w);
        lsum += bce_elem(a[2][0], y2.x) + bce_elem(a[2][1], y2.y)
              + bce_elem(a[2][2], y2.z) + bce_elem(a[2][3], y2.w);
        lsum += bce_elem(a[3][0], y3.x) + bce_elem(a[3][1], y3.y)
              + bce_elem(a[3][2], y3.z) + bce_elem(a[3][3], y3.w);
    }

    float bs = block_reduce_sum(lsum, 256);
    if (tid == 0) part[blockIdx.x] = bs;
}

__global__ void k_final(const float* __restrict__ part, const float* __restrict__ kldp,
                        const float* __restrict__ norm, float* __restrict__ out) {
    double s = 0.0, k = 0.0;
    for (int i = threadIdx.x; i < 2048; i += 256) s += (double)part[i];
    for (int i = threadIdx.x; i < 512; i += 256) k += (double)kldp[i];
    #pragma unroll
    for (int off = 32; off; off >>= 1) {
        s += __shfl_down(s, off, 64);
        k += __shfl_down(k, off, 64);
    }
    __shared__ double ss[4], kk[4];
    int lane = threadIdx.x & 63, wid = threadIdx.x >> 6;
    if (lane == 0) { ss[wid] = s; kk[wid] = k; }
    __syncthreads();
    if (threadIdx.x == 0) {
        double st = ss[0] + ss[1] + ss[2] + ss[3];
        double kt = kk[0] + kk[1] + kk[2] + kk[3];
        double bce = st / ((double)N_NODES * (double)N_NODES);
        double kld = (-0.5 / (double)N_NODES) * (kt / (double)N_NODES);
        out[0] = (float)((double)norm[0] * bce + kld);
    }
}

// ---------------- launch ----------------

extern "C" void kernel_launch(void* const* d_in, const int* in_sizes, int n_in,
                              void* d_out, int out_size, void* d_ws, size_t ws_size,
                              hipStream_t stream) {
    const float* x    = (const float*)d_in[0];
    const int*   ei   = (const int*)d_in[1];
    const int*   adj  = (const int*)d_in[2];
    const float* eps  = (const float*)d_in[3];
    const float* norm = (const float*)d_in[4];
    const float* W1   = (const float*)d_in[5];
    const float* W2   = (const float*)d_in[6];
    const float* W3   = (const float*)d_in[7];
    float* out = (float*)d_out;
    char*  ws  = (char*)d_ws;

    const int* src = ei;
    const int* dst = ei + N_EDGES;

    int*   deg      = (int*)  (ws + 0);        // 32 KB
    int*   cursor   = (int*)  (ws + 32768);    // 32 KB (contiguous with deg)
    int*   rowptr   = (int*)  (ws + 65536);    // 8193 i32 (36 KB slot)
    float* dinv     = (float*)(ws + 102400);   // 32 KB
    int*   csr_src  = (int*)  (ws + 135168);   // 512 KB
    float* csr_coef = (float*)(ws + 659456);   // 512 KB
    float* h        = (float*)(ws + 1183744);  // 1 MB
    float* agg1     = (float*)(ws + 2232320);  // 1 MB
    float* h2mu     = (float*)(ws + 3280896);  // 512 KB
    float* h2lv     = (float*)(ws + 3805184);  // 512 KB
    float* aggmu    = (float*)(ws + 4329472);  // 512 KB
    float* agglv    = (float*)(ws + 4853760);  // 512 KB
    float* zbuf     = (float*)(ws + 5378048);  // 512 KB
    float* part     = (float*)(ws + 5902336);  // 2048 f32
    float* kldp     = (float*)(ws + 5910528);  // 512 f32

    k_init<<<16, 256, 0, stream>>>((float4*)deg);
    k_deg<<<N_EDGES / 256, 256, 0, stream>>>(dst, deg);
    k_scan<<<1, 256, 0, stream>>>(deg, rowptr, dinv);
    k_fill<<<N_EDGES / 256, 256, 0, stream>>>(src, dst, rowptr, dinv, cursor, csr_src, csr_coef);
    k_gemm1<<<N_NODES / 32, 256, 0, stream>>>(x, W1, h);
    k_gather1<<<N_NODES / 4, 256, 0, stream>>>(csr_src, csr_coef, rowptr, h, dinv, agg1);
    k_gemm2<<<N_NODES / 8, 256, 0, stream>>>(agg1, h, dinv, W2, W3, h2mu, h2lv);
    k_gather2<<<N_NODES / 4, 256, 0, stream>>>(csr_src, csr_coef, rowptr, h2mu, h2lv, dinv, aggmu, agglv);
    k_zmu<<<(N_NODES * H2C) / 256, 256, 0, stream>>>(aggmu, agglv, h2mu, h2lv, dinv, eps, zbuf, out, kldp);
    k_bce<<<2048, 256, 0, stream>>>(zbuf, adj, part);
    k_final<<<1, 256, 0, stream>>>(part, kldp, norm, out);
}

// Round 15
// 137.790 us; speedup vs baseline: 2.8744x; 1.0615x over previous
//
#include <hip/hip_runtime.h>
#include <cstdint>
#include <cstddef>

#define N_NODES 8192
#define N_EDGES 131072
#define F_IN    512
#define H1C     32
#define H2C     16

// ---------------- helpers ----------------

__device__ __forceinline__ float block_reduce_sum(float v, int nthreads) {
    #pragma unroll
    for (int off = 32; off; off >>= 1) v += __shfl_down(v, off, 64);
    __shared__ float sred[16];
    int lane = threadIdx.x & 63, wid = threadIdx.x >> 6;
    if (lane == 0) sred[wid] = v;
    __syncthreads();
    float s = 0.0f;
    if (threadIdx.x == 0) {
        int nw = nthreads >> 6;
        for (int i = 0; i < nw; ++i) s += sred[i];
    }
    return s;
}

// POS_WEIGHT=10: y=1 -> 10*softplus(-l); y=0 -> softplus(l).
// Branch-free: sp(l) = lse + relu(l);  val = sp(l)*(1+9y) - 10*y*l
__device__ __forceinline__ float bce_elem(float l, int y) {
    float lse = __logf(1.0f + __expf(-fabsf(l)));
    float sp  = lse + fmaxf(l, 0.0f);
    float w   = (float)y;
    return fmaf(sp, fmaf(9.0f, w, 1.0f), -10.0f * w * l);
}

// force a wave-uniform float into an SGPR
__device__ __forceinline__ float rfl(float x) {
    return __int_as_float(__builtin_amdgcn_readfirstlane(__float_as_int(x)));
}

// ---------------- kernels ----------------

// zero deg + cursor (contiguous 64 KB = 4096 float4)
__global__ void k_init(float4* __restrict__ p) {
    int gid = blockIdx.x * 256 + threadIdx.x;
    float4 zz = {0.0f, 0.0f, 0.0f, 0.0f};
    p[gid] = zz;
}

__global__ void k_deg(const int* __restrict__ dst, int* __restrict__ deg) {
    int e = blockIdx.x * 256 + threadIdx.x;
    if (e < N_EDGES) atomicAdd(&deg[dst[e]], 1);
}

// exclusive scan of deg[8192] -> rowptr[8193], plus dinv[i]=rsqrt(deg+1).
__global__ void k_scan(const int* __restrict__ deg, int* __restrict__ rowptr,
                       float* __restrict__ dinv) {
    int t = threadIdx.x;           // 256
    int base = t * 32;
    int vals[32];
    int s = 0;
    #pragma unroll
    for (int j = 0; j < 32; ++j) {
        vals[j] = deg[base + j];
        s += vals[j];
        dinv[base + j] = rsqrtf((float)(vals[j] + 1));
    }
    int lane = t & 63, wid = t >> 6;
    int inc = s;
    #pragma unroll
    for (int off = 1; off < 64; off <<= 1) {
        int n = __shfl_up(inc, off, 64);
        if (lane >= off) inc += n;
    }
    __shared__ int wsum[4];
    if (lane == 63) wsum[wid] = inc;
    __syncthreads();
    int woff = 0;
    for (int i = 0; i < wid; ++i) woff += wsum[i];
    int run = woff + inc - s;      // exclusive prefix for this thread's chunk
    #pragma unroll
    for (int j = 0; j < 32; ++j) { rowptr[base + j] = run; run += vals[j]; }
    if (t == 255) rowptr[8192] = run;
}

// bucket edges by dst: csr_src/csr_coef
__global__ void k_fill(const int* __restrict__ src, const int* __restrict__ dst,
                       const int* __restrict__ rowptr, const float* __restrict__ dinv,
                       int* __restrict__ cursor, int* __restrict__ csr_src,
                       float* __restrict__ csr_coef) {
    int e = blockIdx.x * 256 + threadIdx.x;
    int d = dst[e], sv = src[e];
    int slot = rowptr[d] + atomicAdd(&cursor[d], 1);
    csr_src[slot] = sv;
    csr_coef[slot] = dinv[sv];
}

// h = x @ W1, barrier-free: W1 staged in LDS once, each thread streams its x row
__global__ void __launch_bounds__(256)
k_gemm1(const float* __restrict__ x, const float* __restrict__ W1,
        float* __restrict__ h) {
    __shared__ float wsm[F_IN][H1C];   // 64 KB
    int tid = threadIdx.x;
    {
        float4* wd = (float4*)wsm;
        const float4* wsrc = (const float4*)W1;
        #pragma unroll
        for (int i = 0; i < 16; ++i) wd[tid + i * 256] = wsrc[tid + i * 256];
    }
    __syncthreads();

    int row = (blockIdx.x << 5) + (tid >> 3);
    int c4 = (tid & 7) << 2;
    const float4* xp = (const float4*)&x[(size_t)row * F_IN];

    float ax = 0.f, ay = 0.f, az = 0.f, aw = 0.f;
    #pragma unroll 8
    for (int k4 = 0; k4 < F_IN / 4; ++k4) {
        float4 xv = xp[k4];
        float4 w0 = *(const float4*)&wsm[k4 * 4 + 0][c4];
        float4 w1 = *(const float4*)&wsm[k4 * 4 + 1][c4];
        float4 w2 = *(const float4*)&wsm[k4 * 4 + 2][c4];
        float4 w3 = *(const float4*)&wsm[k4 * 4 + 3][c4];
        ax = fmaf(xv.x, w0.x, ax); ay = fmaf(xv.x, w0.y, ay);
        az = fmaf(xv.x, w0.z, az); aw = fmaf(xv.x, w0.w, aw);
        ax = fmaf(xv.y, w1.x, ax); ay = fmaf(xv.y, w1.y, ay);
        az = fmaf(xv.y, w1.z, az); aw = fmaf(xv.y, w1.w, aw);
        ax = fmaf(xv.z, w2.x, ax); ay = fmaf(xv.z, w2.y, ay);
        az = fmaf(xv.z, w2.z, az); aw = fmaf(xv.z, w2.w, aw);
        ax = fmaf(xv.w, w3.x, ax); ay = fmaf(xv.w, w3.y, ay);
        az = fmaf(xv.w, w3.z, az); aw = fmaf(xv.w, w3.w, aw);
    }
    float4 v; v.x = ax; v.y = ay; v.z = az; v.w = aw;
    *(float4*)&h[(size_t)row * H1C + c4] = v;
}

// FUSED gather1 + gemm2: wave owns a dst row. Gather agg1 (32 feats x 2
// halves), combine, build h1 row in LDS (wave-synchronous), then each lane
// computes one output col of h1@W2 (lanes 0-15) / h1@W3 (lanes 16-31).
__global__ void __launch_bounds__(256)
k_g1g2(const int* __restrict__ csr_src, const float* __restrict__ csr_coef,
       const int* __restrict__ rowptr, const float* __restrict__ h,
       const float* __restrict__ dinv, const float* __restrict__ W2,
       const float* __restrict__ W3, float* __restrict__ h2mu,
       float* __restrict__ h2lv) {
    __shared__ float w2s[H1C * H2C], w3s[H1C * H2C];
    __shared__ float h1s[4][33];
    int tid = threadIdx.x;
    {
        w2s[tid] = W2[tid]; w2s[tid + 256] = W2[tid + 256];
        w3s[tid] = W3[tid]; w3s[tid + 256] = W3[tid + 256];
    }
    __syncthreads();

    int w = tid >> 6;
    int row = blockIdx.x * 4 + w;
    int lane = tid & 63;
    int f = lane & 31, half = lane >> 5;
    int beg = rowptr[row], end = rowptr[row + 1];
    float acc = 0.0f;
    for (int sl = beg + half; sl < end; sl += 2) {
        int s = csr_src[sl];
        float c = csr_coef[sl];
        acc = fmaf(h[(s << 5) + f], c, acc);
    }
    acc += __shfl_down(acc, 32, 64);
    if (half == 0) {
        float di = dinv[row], d2 = di * di;
        float a1 = acc * di;
        h1s[w][f] = fmaxf(fmaf(h[(row << 5) + f], d2, a1), 0.0f);
    }
    // wave-synchronous LDS write->read (no block barrier needed)
    if (half == 0) {
        const float* wsrc = (f < 16) ? w2s : w3s;
        int col = f & 15;
        float o = 0.0f;
        #pragma unroll
        for (int k = 0; k < H1C; ++k) o = fmaf(h1s[w][k], wsrc[(k << 4) + col], o);
        if (f < 16) h2mu[(row << 4) + col] = o;
        else        h2lv[(row << 4) + col] = o;
    }
}

// FUSED gather2 + zmu: wave owns a row (lanes 0-15 mu, 16-31 lv), gathers
// edge aggregates, adds self-loop, shfl_xor(16) swaps mu<->lv, then lanes
// 0-15 finalize z/mu/kld. aggmu/agglv buffers eliminated.
__global__ void __launch_bounds__(256)
k_g2z(const int* __restrict__ csr_src, const float* __restrict__ csr_coef,
      const int* __restrict__ rowptr, const float* __restrict__ h2mu,
      const float* __restrict__ h2lv, const float* __restrict__ dinv,
      const float* __restrict__ eps, float* __restrict__ zbuf,
      float* __restrict__ out, float* __restrict__ kldp) {
    int tid = threadIdx.x;
    int row = blockIdx.x * 4 + (tid >> 6);
    int lane = tid & 63;
    int f = lane & 31, half = lane >> 5;
    int ff = f & 15;
    const float* hsrc = (f < 16) ? h2mu : h2lv;
    int beg = rowptr[row], end = rowptr[row + 1];
    float acc = 0.0f;
    for (int sl = beg + half; sl < end; sl += 2) {
        int s = csr_src[sl];
        float c = csr_coef[sl];
        acc = fmaf(hsrc[(s << 4) + ff], c, acc);
    }
    acc += __shfl_down(acc, 32, 64);
    float di = dinv[row], d2 = di * di;
    float val = fmaf(hsrc[(row << 4) + ff], d2, acc * di);  // mu (f<16) or lv
    float other = __shfl_xor(val, 16, 64);                  // swap mu<->lv
    float kterm = 0.0f;
    if (half == 0 && f < 16) {
        float m = val, lv = other;
        float el = __expf(lv);
        float zv = fmaf(eps[(row << 4) + ff], el, m);
        zbuf[(row << 4) + ff] = zv;
        out[1 + (row << 4) + ff] = m;
        kterm = 1.0f + 2.0f * lv - m * m - el * el;
    }
    float bs = block_reduce_sum(kterm, 256);
    if (tid == 0) kldp[blockIdx.x] = bs;
}

// ---- BCE v3: barrier-free, 16 bands x 2 cols/thread (4096 blocks).
// zc[2][16] = 32 VGPR (was 64) -> ~70-80 VGPR total -> 6-7 waves/SIMD for
// latency hiding (r13/14 was ~3). adj loads int2 (512B/wave, coalesced).
__global__ void __launch_bounds__(256)
k_bce(const float* __restrict__ z, const int* __restrict__ adj,
      float* __restrict__ part) {
    int tid = threadIdx.x;
    int band = blockIdx.x & 15;
    int rblk = blockIdx.x >> 4;
    int col0 = (band << 9) + (tid << 1);   // 2 cols per thread
    int row0 = rblk << 5;

    // zc: 2 cols x 16 k (128B contiguous, loaded once)
    float zc[2][16];
    {
        const float4* zp = (const float4*)&z[(size_t)col0 * H2C];
        #pragma unroll
        for (int q = 0; q < 8; ++q) {
            float4 v = zp[q];
            int c = q >> 2, qq = (q & 3) << 2;
            zc[c][qq + 0] = v.x; zc[c][qq + 1] = v.y;
            zc[c][qq + 2] = v.z; zc[c][qq + 3] = v.w;
        }
    }

    float lsum = 0.0f;
    #pragma unroll
    for (int step = 0; step < 8; ++step) {
        int r0 = row0 + (step << 2);
        const int* ap = adj + (size_t)r0 * N_NODES + col0;
        int2 y0 = *(const int2*)(ap);
        int2 y1 = *(const int2*)(ap + N_NODES);
        int2 y2 = *(const int2*)(ap + 2 * N_NODES);
        int2 y3 = *(const int2*)(ap + 3 * N_NODES);

        // wave-uniform z rows: 16 float4 L1-broadcast loads -> SGPRs
        float zr[4][16];
        {
            const float4* zp = (const float4*)&z[(size_t)r0 * H2C];
            #pragma unroll
            for (int q = 0; q < 16; ++q) {
                float4 v = zp[q];
                int r = q >> 2, qq = (q & 3) << 2;
                zr[r][qq + 0] = rfl(v.x); zr[r][qq + 1] = rfl(v.y);
                zr[r][qq + 2] = rfl(v.z); zr[r][qq + 3] = rfl(v.w);
            }
        }

        float a[4][2];
        #pragma unroll
        for (int r = 0; r < 4; ++r) { a[r][0] = 0.0f; a[r][1] = 0.0f; }
        #pragma unroll
        for (int k = 0; k < 16; ++k) {
            #pragma unroll
            for (int r = 0; r < 4; ++r) {
                float zv = zr[r][k];
                a[r][0] = fmaf(zv, zc[0][k], a[r][0]);
                a[r][1] = fmaf(zv, zc[1][k], a[r][1]);
            }
        }
        lsum += bce_elem(a[0][0], y0.x) + bce_elem(a[0][1], y0.y);
        lsum += bce_elem(a[1][0], y1.x) + bce_elem(a[1][1], y1.y);
        lsum += bce_elem(a[2][0], y2.x) + bce_elem(a[2][1], y2.y);
        lsum += bce_elem(a[3][0], y3.x) + bce_elem(a[3][1], y3.y);
    }

    float bs = block_reduce_sum(lsum, 256);
    if (tid == 0) part[blockIdx.x] = bs;
}

__global__ void k_final(const float* __restrict__ part, const float* __restrict__ kldp,
                        const float* __restrict__ norm, float* __restrict__ out) {
    double s = 0.0, k = 0.0;
    for (int i = threadIdx.x; i < 4096; i += 256) s += (double)part[i];
    for (int i = threadIdx.x; i < 2048; i += 256) k += (double)kldp[i];
    #pragma unroll
    for (int off = 32; off; off >>= 1) {
        s += __shfl_down(s, off, 64);
        k += __shfl_down(k, off, 64);
    }
    __shared__ double ss[4], kk[4];
    int lane = threadIdx.x & 63, wid = threadIdx.x >> 6;
    if (lane == 0) { ss[wid] = s; kk[wid] = k; }
    __syncthreads();
    if (threadIdx.x == 0) {
        double st = ss[0] + ss[1] + ss[2] + ss[3];
        double kt = kk[0] + kk[1] + kk[2] + kk[3];
        double bce = st / ((double)N_NODES * (double)N_NODES);
        double kld = (-0.5 / (double)N_NODES) * (kt / (double)N_NODES);
        out[0] = (float)((double)norm[0] * bce + kld);
    }
}

// ---------------- launch ----------------

extern "C" void kernel_launch(void* const* d_in, const int* in_sizes, int n_in,
                              void* d_out, int out_size, void* d_ws, size_t ws_size,
                              hipStream_t stream) {
    const float* x    = (const float*)d_in[0];
    const int*   ei   = (const int*)d_in[1];
    const int*   adj  = (const int*)d_in[2];
    const float* eps  = (const float*)d_in[3];
    const float* norm = (const float*)d_in[4];
    const float* W1   = (const float*)d_in[5];
    const float* W2   = (const float*)d_in[6];
    const float* W3   = (const float*)d_in[7];
    float* out = (float*)d_out;
    char*  ws  = (char*)d_ws;

    const int* src = ei;
    const int* dst = ei + N_EDGES;

    int*   deg      = (int*)  (ws + 0);        // 32 KB
    int*   cursor   = (int*)  (ws + 32768);    // 32 KB (contiguous with deg)
    int*   rowptr   = (int*)  (ws + 65536);    // 8193 i32 (36 KB slot)
    float* dinv     = (float*)(ws + 102400);   // 32 KB
    int*   csr_src  = (int*)  (ws + 135168);   // 512 KB
    float* csr_coef = (float*)(ws + 659456);   // 512 KB
    float* h        = (float*)(ws + 1183744);  // 1 MB
    float* h2mu     = (float*)(ws + 3280896);  // 512 KB
    float* h2lv     = (float*)(ws + 3805184);  // 512 KB
    float* zbuf     = (float*)(ws + 5378048);  // 512 KB
    float* part     = (float*)(ws + 5902336);  // 4096 f32
    float* kldp     = (float*)(ws + 5918720);  // 2048 f32

    k_init<<<16, 256, 0, stream>>>((float4*)deg);
    k_deg<<<N_EDGES / 256, 256, 0, stream>>>(dst, deg);
    k_scan<<<1, 256, 0, stream>>>(deg, rowptr, dinv);
    k_fill<<<N_EDGES / 256, 256, 0, stream>>>(src, dst, rowptr, dinv, cursor, csr_src, csr_coef);
    k_gemm1<<<N_NODES / 32, 256, 0, stream>>>(x, W1, h);
    k_g1g2<<<N_NODES / 4, 256, 0, stream>>>(csr_src, csr_coef, rowptr, h, dinv, W2, W3, h2mu, h2lv);
    k_g2z<<<N_NODES / 4, 256, 0, stream>>>(csr_src, csr_coef, rowptr, h2mu, h2lv, dinv, eps, zbuf, out, kldp);
    k_bce<<<4096, 256, 0, stream>>>(zbuf, adj, part);
    k_final<<<1, 256, 0, stream>>>(part, kldp, norm, out);
}

// Round 16
// 132.352 us; speedup vs baseline: 2.9925x; 1.0411x over previous
//
#include <hip/hip_runtime.h>
#include <cstdint>
#include <cstddef>

#define N_NODES 8192
#define N_EDGES 131072
#define F_IN    512
#define H1C     32
#define H2C     16

// ---------------- helpers ----------------

__device__ __forceinline__ float block_reduce_sum(float v, int nthreads) {
    #pragma unroll
    for (int off = 32; off; off >>= 1) v += __shfl_down(v, off, 64);
    __shared__ float sred[16];
    int lane = threadIdx.x & 63, wid = threadIdx.x >> 6;
    if (lane == 0) sred[wid] = v;
    __syncthreads();
    float s = 0.0f;
    if (threadIdx.x == 0) {
        int nw = nthreads >> 6;
        for (int i = 0; i < nw; ++i) s += sred[i];
    }
    return s;
}

// POS_WEIGHT=10: y=1 -> 10*softplus(-l); y=0 -> softplus(l).
// Branch-free: sp(l) = lse + relu(l);  val = sp(l)*(1+9y) - 10*y*l
__device__ __forceinline__ float bce_elem(float l, int y) {
    float lse = __logf(1.0f + __expf(-fabsf(l)));
    float sp  = lse + fmaxf(l, 0.0f);
    float w   = (float)y;
    return fmaf(sp, fmaf(9.0f, w, 1.0f), -10.0f * w * l);
}

// ---------------- kernels ----------------

// zero deg + cursor (contiguous 64 KB = 4096 float4)
__global__ void k_init(float4* __restrict__ p) {
    int gid = blockIdx.x * 256 + threadIdx.x;
    float4 zz = {0.0f, 0.0f, 0.0f, 0.0f};
    p[gid] = zz;
}

__global__ void k_deg(const int* __restrict__ dst, int* __restrict__ deg) {
    int e = blockIdx.x * 256 + threadIdx.x;
    if (e < N_EDGES) atomicAdd(&deg[dst[e]], 1);
}

// exclusive scan of deg[8192] -> rowptr[8193], plus dinv[i]=rsqrt(deg+1).
__global__ void k_scan(const int* __restrict__ deg, int* __restrict__ rowptr,
                       float* __restrict__ dinv) {
    int t = threadIdx.x;           // 256
    int base = t * 32;
    int vals[32];
    int s = 0;
    #pragma unroll
    for (int j = 0; j < 32; ++j) {
        vals[j] = deg[base + j];
        s += vals[j];
        dinv[base + j] = rsqrtf((float)(vals[j] + 1));
    }
    int lane = t & 63, wid = t >> 6;
    int inc = s;
    #pragma unroll
    for (int off = 1; off < 64; off <<= 1) {
        int n = __shfl_up(inc, off, 64);
        if (lane >= off) inc += n;
    }
    __shared__ int wsum[4];
    if (lane == 63) wsum[wid] = inc;
    __syncthreads();
    int woff = 0;
    for (int i = 0; i < wid; ++i) woff += wsum[i];
    int run = woff + inc - s;      // exclusive prefix for this thread's chunk
    #pragma unroll
    for (int j = 0; j < 32; ++j) { rowptr[base + j] = run; run += vals[j]; }
    if (t == 255) rowptr[8192] = run;
}

// bucket edges by dst: csr_src/csr_coef
__global__ void k_fill(const int* __restrict__ src, const int* __restrict__ dst,
                       const int* __restrict__ rowptr, const float* __restrict__ dinv,
                       int* __restrict__ cursor, int* __restrict__ csr_src,
                       float* __restrict__ csr_coef) {
    int e = blockIdx.x * 256 + threadIdx.x;
    int d = dst[e], sv = src[e];
    int slot = rowptr[d] + atomicAdd(&cursor[d], 1);
    csr_src[slot] = sv;
    csr_coef[slot] = dinv[sv];
}

// h = x @ W1, barrier-free: W1 staged in LDS once, each thread streams its x row
__global__ void __launch_bounds__(256)
k_gemm1(const float* __restrict__ x, const float* __restrict__ W1,
        float* __restrict__ h) {
    __shared__ float wsm[F_IN][H1C];   // 64 KB
    int tid = threadIdx.x;
    {
        float4* wd = (float4*)wsm;
        const float4* wsrc = (const float4*)W1;
        #pragma unroll
        for (int i = 0; i < 16; ++i) wd[tid + i * 256] = wsrc[tid + i * 256];
    }
    __syncthreads();

    int row = (blockIdx.x << 5) + (tid >> 3);
    int c4 = (tid & 7) << 2;
    const float4* xp = (const float4*)&x[(size_t)row * F_IN];

    float ax = 0.f, ay = 0.f, az = 0.f, aw = 0.f;
    #pragma unroll 8
    for (int k4 = 0; k4 < F_IN / 4; ++k4) {
        float4 xv = xp[k4];
        float4 w0 = *(const float4*)&wsm[k4 * 4 + 0][c4];
        float4 w1 = *(const float4*)&wsm[k4 * 4 + 1][c4];
        float4 w2 = *(const float4*)&wsm[k4 * 4 + 2][c4];
        float4 w3 = *(const float4*)&wsm[k4 * 4 + 3][c4];
        ax = fmaf(xv.x, w0.x, ax); ay = fmaf(xv.x, w0.y, ay);
        az = fmaf(xv.x, w0.z, az); aw = fmaf(xv.x, w0.w, aw);
        ax = fmaf(xv.y, w1.x, ax); ay = fmaf(xv.y, w1.y, ay);
        az = fmaf(xv.y, w1.z, az); aw = fmaf(xv.y, w1.w, aw);
        ax = fmaf(xv.z, w2.x, ax); ay = fmaf(xv.z, w2.y, ay);
        az = fmaf(xv.z, w2.z, az); aw = fmaf(xv.z, w2.w, aw);
        ax = fmaf(xv.w, w3.x, ax); ay = fmaf(xv.w, w3.y, ay);
        az = fmaf(xv.w, w3.z, az); aw = fmaf(xv.w, w3.w, aw);
    }
    float4 v; v.x = ax; v.y = ay; v.z = az; v.w = aw;
    *(float4*)&h[(size_t)row * H1C + c4] = v;
}

// FUSED gather1 + gemm2: wave owns a dst row. Gather agg1 (32 feats x 2
// halves), combine, build h1 row in LDS (wave-synchronous), then each lane
// computes one output col of h1@W2 (lanes 0-15) / h1@W3 (lanes 16-31).
__global__ void __launch_bounds__(256)
k_g1g2(const int* __restrict__ csr_src, const float* __restrict__ csr_coef,
       const int* __restrict__ rowptr, const float* __restrict__ h,
       const float* __restrict__ dinv, const float* __restrict__ W2,
       const float* __restrict__ W3, float* __restrict__ h2mu,
       float* __restrict__ h2lv) {
    __shared__ float w2s[H1C * H2C], w3s[H1C * H2C];
    __shared__ float h1s[4][33];
    int tid = threadIdx.x;
    {
        w2s[tid] = W2[tid]; w2s[tid + 256] = W2[tid + 256];
        w3s[tid] = W3[tid]; w3s[tid + 256] = W3[tid + 256];
    }
    __syncthreads();

    int w = tid >> 6;
    int row = blockIdx.x * 4 + w;
    int lane = tid & 63;
    int f = lane & 31, half = lane >> 5;
    int beg = rowptr[row], end = rowptr[row + 1];
    float acc = 0.0f;
    for (int sl = beg + half; sl < end; sl += 2) {
        int s = csr_src[sl];
        float c = csr_coef[sl];
        acc = fmaf(h[(s << 5) + f], c, acc);
    }
    acc += __shfl_down(acc, 32, 64);
    if (half == 0) {
        float di = dinv[row], d2 = di * di;
        float a1 = acc * di;
        h1s[w][f] = fmaxf(fmaf(h[(row << 5) + f], d2, a1), 0.0f);
    }
    // wave-synchronous LDS write->read (no block barrier needed)
    if (half == 0) {
        const float* wsrc = (f < 16) ? w2s : w3s;
        int col = f & 15;
        float o = 0.0f;
        #pragma unroll
        for (int k = 0; k < H1C; ++k) o = fmaf(h1s[w][k], wsrc[(k << 4) + col], o);
        if (f < 16) h2mu[(row << 4) + col] = o;
        else        h2lv[(row << 4) + col] = o;
    }
}

// FUSED gather2 + zmu: wave owns a row (lanes 0-15 mu, 16-31 lv), gathers
// edge aggregates, adds self-loop, shfl_xor(16) swaps mu<->lv, then lanes
// 0-15 finalize z/mu/kld.
__global__ void __launch_bounds__(256)
k_g2z(const int* __restrict__ csr_src, const float* __restrict__ csr_coef,
      const int* __restrict__ rowptr, const float* __restrict__ h2mu,
      const float* __restrict__ h2lv, const float* __restrict__ dinv,
      const float* __restrict__ eps, float* __restrict__ zbuf,
      float* __restrict__ out, float* __restrict__ kldp) {
    int tid = threadIdx.x;
    int row = blockIdx.x * 4 + (tid >> 6);
    int lane = tid & 63;
    int f = lane & 31, half = lane >> 5;
    int ff = f & 15;
    const float* hsrc = (f < 16) ? h2mu : h2lv;
    int beg = rowptr[row], end = rowptr[row + 1];
    float acc = 0.0f;
    for (int sl = beg + half; sl < end; sl += 2) {
        int s = csr_src[sl];
        float c = csr_coef[sl];
        acc = fmaf(hsrc[(s << 4) + ff], c, acc);
    }
    acc += __shfl_down(acc, 32, 64);
    float di = dinv[row], d2 = di * di;
    float val = fmaf(hsrc[(row << 4) + ff], d2, acc * di);  // mu (f<16) or lv
    float other = __shfl_xor(val, 16, 64);                  // swap mu<->lv
    float kterm = 0.0f;
    if (half == 0 && f < 16) {
        float m = val, lv = other;
        float el = __expf(lv);
        float zv = fmaf(eps[(row << 4) + ff], el, m);
        zbuf[(row << 4) + ff] = zv;
        out[1 + (row << 4) + ff] = m;
        kterm = 1.0f + 2.0f * lv - m * m - el * el;
    }
    float bs = block_reduce_sum(kterm, 256);
    if (tid == 0) kldp[blockIdx.x] = bs;
}

// ---- BCE v4: barrier-free hot loop, 16 bands x 2 cols/thread (4096 blocks).
// zr REWORK vs r15: block's 32 z-rows staged ONCE into transposed LDS
// zrT[16][32] (2 KB); per step+k one ds_read_b128 of zrT[k][r0..r0+3] —
// all lanes same address -> LDS broadcast, conflict-free. Removes 128
// wave-uniform global loads + 512 readfirstlane per thread (4x the payload
// load count, ~1/5 of VALU) and empties the VMEM queue for adj overlap.
// VGPR ~60 -> 7-8 waves/SIMD.
__global__ void __launch_bounds__(256)
k_bce(const float* __restrict__ z, const int* __restrict__ adj,
      float* __restrict__ part) {
    __shared__ float zrT[16][32];      // [k][row], 2 KB
    int tid = threadIdx.x;
    int band = blockIdx.x & 15;
    int rblk = blockIdx.x >> 4;
    int col0 = (band << 9) + (tid << 1);   // 2 cols per thread
    int row0 = rblk << 5;

    // stage zrT (32 rows x 16 k, transposed) — 128 threads, once
    if (tid < 128) {
        int r = tid >> 2, q = (tid & 3) << 2;
        float4 v = *(const float4*)&z[(size_t)(row0 + r) * H2C + q];
        zrT[q + 0][r] = v.x; zrT[q + 1][r] = v.y;
        zrT[q + 2][r] = v.z; zrT[q + 3][r] = v.w;
    }

    // zc: 2 cols x 16 k (128B contiguous, loaded once)
    float zc[2][16];
    {
        const float4* zp = (const float4*)&z[(size_t)col0 * H2C];
        #pragma unroll
        for (int q = 0; q < 8; ++q) {
            float4 v = zp[q];
            int c = q >> 2, qq = (q & 3) << 2;
            zc[c][qq + 0] = v.x; zc[c][qq + 1] = v.y;
            zc[c][qq + 2] = v.z; zc[c][qq + 3] = v.w;
        }
    }
    __syncthreads();

    float lsum = 0.0f;
    #pragma unroll
    for (int step = 0; step < 8; ++step) {
        int r0 = step << 2;
        const int* ap = adj + (size_t)(row0 + r0) * N_NODES + col0;
        int2 y0 = *(const int2*)(ap);
        int2 y1 = *(const int2*)(ap + N_NODES);
        int2 y2 = *(const int2*)(ap + 2 * N_NODES);
        int2 y3 = *(const int2*)(ap + 3 * N_NODES);

        float a[4][2];
        #pragma unroll
        for (int r = 0; r < 4; ++r) { a[r][0] = 0.0f; a[r][1] = 0.0f; }
        #pragma unroll
        for (int k = 0; k < 16; ++k) {
            float4 zr4 = *(const float4*)&zrT[k][r0];   // LDS broadcast
            a[0][0] = fmaf(zr4.x, zc[0][k], a[0][0]);
            a[0][1] = fmaf(zr4.x, zc[1][k], a[0][1]);
            a[1][0] = fmaf(zr4.y, zc[0][k], a[1][0]);
            a[1][1] = fmaf(zr4.y, zc[1][k], a[1][1]);
            a[2][0] = fmaf(zr4.z, zc[0][k], a[2][0]);
            a[2][1] = fmaf(zr4.z, zc[1][k], a[2][1]);
            a[3][0] = fmaf(zr4.w, zc[0][k], a[3][0]);
            a[3][1] = fmaf(zr4.w, zc[1][k], a[3][1]);
        }
        lsum += bce_elem(a[0][0], y0.x) + bce_elem(a[0][1], y0.y);
        lsum += bce_elem(a[1][0], y1.x) + bce_elem(a[1][1], y1.y);
        lsum += bce_elem(a[2][0], y2.x) + bce_elem(a[2][1], y2.y);
        lsum += bce_elem(a[3][0], y3.x) + bce_elem(a[3][1], y3.y);
    }

    float bs = block_reduce_sum(lsum, 256);
    if (tid == 0) part[blockIdx.x] = bs;
}

__global__ void k_final(const float* __restrict__ part, const float* __restrict__ kldp,
                        const float* __restrict__ norm, float* __restrict__ out) {
    double s = 0.0, k = 0.0;
    for (int i = threadIdx.x; i < 4096; i += 256) s += (double)part[i];
    for (int i = threadIdx.x; i < 2048; i += 256) k += (double)kldp[i];
    #pragma unroll
    for (int off = 32; off; off >>= 1) {
        s += __shfl_down(s, off, 64);
        k += __shfl_down(k, off, 64);
    }
    __shared__ double ss[4], kk[4];
    int lane = threadIdx.x & 63, wid = threadIdx.x >> 6;
    if (lane == 0) { ss[wid] = s; kk[wid] = k; }
    __syncthreads();
    if (threadIdx.x == 0) {
        double st = ss[0] + ss[1] + ss[2] + ss[3];
        double kt = kk[0] + kk[1] + kk[2] + kk[3];
        double bce = st / ((double)N_NODES * (double)N_NODES);
        double kld = (-0.5 / (double)N_NODES) * (kt / (double)N_NODES);
        out[0] = (float)((double)norm[0] * bce + kld);
    }
}

// ---------------- launch ----------------

extern "C" void kernel_launch(void* const* d_in, const int* in_sizes, int n_in,
                              void* d_out, int out_size, void* d_ws, size_t ws_size,
                              hipStream_t stream) {
    const float* x    = (const float*)d_in[0];
    const int*   ei   = (const int*)d_in[1];
    const int*   adj  = (const int*)d_in[2];
    const float* eps  = (const float*)d_in[3];
    const float* norm = (const float*)d_in[4];
    const float* W1   = (const float*)d_in[5];
    const float* W2   = (const float*)d_in[6];
    const float* W3   = (const float*)d_in[7];
    float* out = (float*)d_out;
    char*  ws  = (char*)d_ws;

    const int* src = ei;
    const int* dst = ei + N_EDGES;

    int*   deg      = (int*)  (ws + 0);        // 32 KB
    int*   cursor   = (int*)  (ws + 32768);    // 32 KB (contiguous with deg)
    int*   rowptr   = (int*)  (ws + 65536);    // 8193 i32 (36 KB slot)
    float* dinv     = (float*)(ws + 102400);   // 32 KB
    int*   csr_src  = (int*)  (ws + 135168);   // 512 KB
    float* csr_coef = (float*)(ws + 659456);   // 512 KB
    float* h        = (float*)(ws + 1183744);  // 1 MB
    float* h2mu     = (float*)(ws + 3280896);  // 512 KB
    float* h2lv     = (float*)(ws + 3805184);  // 512 KB
    float* zbuf     = (float*)(ws + 5378048);  // 512 KB
    float* part     = (float*)(ws + 5902336);  // 4096 f32
    float* kldp     = (float*)(ws + 5918720);  // 2048 f32

    k_init<<<16, 256, 0, stream>>>((float4*)deg);
    k_deg<<<N_EDGES / 256, 256, 0, stream>>>(dst, deg);
    k_scan<<<1, 256, 0, stream>>>(deg, rowptr, dinv);
    k_fill<<<N_EDGES / 256, 256, 0, stream>>>(src, dst, rowptr, dinv, cursor, csr_src, csr_coef);
    k_gemm1<<<N_NODES / 32, 256, 0, stream>>>(x, W1, h);
    k_g1g2<<<N_NODES / 4, 256, 0, stream>>>(csr_src, csr_coef, rowptr, h, dinv, W2, W3, h2mu, h2lv);
    k_g2z<<<N_NODES / 4, 256, 0, stream>>>(csr_src, csr_coef, rowptr, h2mu, h2lv, dinv, eps, zbuf, out, kldp);
    k_bce<<<4096, 256, 0, stream>>>(zbuf, adj, part);
    k_final<<<1, 256, 0, stream>>>(part, kldp, norm, out);
}